// Round 4
// baseline (490.414 us; speedup 1.0000x reference)
//
#include <hip/hip_runtime.h>

#define Bn 65536
#define Tn 100
#define Cn 7

__device__ __forceinline__ float fast_rcp(float x) { return __builtin_amdgcn_rcpf(x); }
__device__ __forceinline__ float sig_f(float x) { return fast_rcp(1.f + __expf(-x)); }
// tanh(x) = 1 - 2/(e^{2x}+1): saturates cleanly to +/-1, no inf/inf NaN
__device__ __forceinline__ float tanh_f(float x) { return 1.f - 2.f * fast_rcp(__expf(2.f * x) + 1.f); }
// SGPR broadcast of lane l's value to the whole wave (lane index compile-time const)
__device__ __forceinline__ float rdlane(float v, int l) {
    return __int_as_float(__builtin_amdgcn_readlane(__float_as_int(v), l));
}

typedef const __attribute__((address_space(1))) void* gp_t;
typedef __attribute__((address_space(3))) void* sp_t;
// async global->LDS dword copy: per-lane global gather; LDS dest = first-active-lane base + lane*4
__device__ __forceinline__ void async_copy_dw(const float* g, float* l) {
    __builtin_amdgcn_global_load_lds((gp_t)g, (sp_t)l, 4, 0, 0);
}

// ---------------- K0: transpose fc1_w (64,400) -> fc1_wt (400,64) ----------------
__global__ void fc1t_kernel(const float* __restrict__ fc1_w, float* __restrict__ fc1_wt) {
    int idx = blockIdx.x * 256 + threadIdx.x;  // 25600 total
    if (idx < 400 * 64) {
        int col = idx >> 6;
        int k = idx & 63;
        fc1_wt[idx] = fc1_w[k * 400 + col];
    }
}

// ---------------- K1: bidirectional LSTM layer 0 ----------------
// 512 blocks x 256: 128 samples/block, tid<128 fwd, tid>=128 rev.
// Double-buffered 5-step chunks staged via async global_load_lds into flat stride-35
// LDS (2-way bank aliasing = free). Chunk ch+1 issued right after the chunk-ch barrier:
// HBM latency hides under the 5-step compute. One barrier per chunk.
// h1 written as float2 [T][2][B] (plane=dir) -> one 8B store/step, coalesced for layer 1.
__global__ __launch_bounds__(256) void l0_kernel(
    const float* __restrict__ x,
    const float* __restrict__ wih_f, const float* __restrict__ whh_f,
    const float* __restrict__ bih_f, const float* __restrict__ bhh_f,
    const float* __restrict__ wih_r, const float* __restrict__ whh_r,
    const float* __restrict__ bih_r, const float* __restrict__ bhh_r,
    float2* __restrict__ h1f2)
{
    __shared__ float xs[2][2][4480];   // [parity][dir][128 samples * 35 floats] = 71,680 B

    const int tid  = threadIdx.x;
    const int rev  = tid >> 7;        // wave-uniform (waves 0,1 fwd; 2,3 rev)
    const int s    = tid & 127;
    const int b    = blockIdx.x * 128 + s;
    const int w    = tid >> 6;        // wave 0..3
    const int lane = tid & 63;
    const int sdir = w >> 1;          // which dir buffer this wave stages
    const int half = w & 1;           // which 64-sample half this wave stages

    const float* wih = rev ? wih_r : wih_f;
    const float* whh = rev ? whh_r : whh_f;
    const float* bih = rev ? bih_r : bih_f;
    const float* bhh = rev ? bhh_r : bhh_f;

    float wi[56], wh[16], bias[8];
#pragma unroll
    for (int k = 0; k < 56; ++k) wi[k] = wih[k];
#pragma unroll
    for (int k = 0; k < 16; ++k) wh[k] = whh[k];
#pragma unroll
    for (int k = 0; k < 8; ++k) bias[k] = bih[k] + bhh[k];

    // staging-invariant per-lane init: flat span float f0 = half*2240 + lane
    const int e  = (lane >= 35) ? 1 : 0;
    const int r0 = lane - 35 * e;             // offset within 35-float row
    const int s0 = half * 64 + e;             // block-local sample
    const float* xsamp = x + (size_t)(blockIdx.x * 128 + s0) * 700;

    // 35 async dword gathers for chunk ch of this wave's dir into parity p.
    // f advances by 64 per issue: r += 29 (wrap -6, samples +2) -> branchless.
    auto stage = [&](int ch, int p) {
        const int off = sdir ? (665 - 35 * ch) : (35 * ch);  // row-start float of chunk
        const float* g = xsamp + off + r0;
        float* l = &xs[p][sdir][half * 2240 + lane];
        int r = r0;
#pragma unroll
        for (int i = 0; i < 35; ++i) {
            async_copy_dw(g, l);
            l += 64;
            const int c = (r >= 6) ? 1 : 0;
            g += c ? 1394 : 729;              // (2*700-6) : (700+29) floats
            r += c ? -6 : 29;
        }
    };

    float h0 = 0.f, h1v = 0.f, c0 = 0.f, c1 = 0.f;

    stage(0, 0);
#pragma unroll 1
    for (int ch = 0; ch < 20; ++ch) {
        __builtin_amdgcn_s_waitcnt(0);        // chunk ch arrived (issued one compute-phase ago)
        __syncthreads();
        if (ch < 19) stage(ch + 1, (ch + 1) & 1);   // overlap with compute below

        const int t0 = rev ? (95 - 5 * ch) : (5 * ch);
        const float* xbuf = &xs[ch & 1][rev][0];
#pragma unroll 1
        for (int tt = 0; tt < 5; ++tt) {
            const int rr = rev ? (4 - tt) : tt;
            const int t  = t0 + rr;
            const float* xrow = xbuf + s * 35 + rr * 7;

            float g[8];
#pragma unroll
            for (int k = 0; k < 8; ++k) g[k] = bias[k];
#pragma unroll
            for (int c = 0; c < 7; ++c) {
                const float xv = xrow[c];
#pragma unroll
                for (int k = 0; k < 8; ++k) g[k] = fmaf(wi[k * 7 + c], xv, g[k]);
            }
#pragma unroll
            for (int k = 0; k < 8; ++k)
                g[k] = fmaf(wh[k * 2], h0, fmaf(wh[k * 2 + 1], h1v, g[k]));

            const float i0 = sig_f(g[0]), i1 = sig_f(g[1]);
            const float f0 = sig_f(g[2]), f1 = sig_f(g[3]);
            const float q0 = tanh_f(g[4]), q1 = tanh_f(g[5]);
            const float o0 = sig_f(g[6]), o1 = sig_f(g[7]);
            c0 = fmaf(f0, c0, i0 * q0);
            c1 = fmaf(f1, c1, i1 * q1);
            h0  = o0 * tanh_f(c0);
            h1v = o1 * tanh_f(c1);

            h1f2[((size_t)t * 2 + rev) * Bn + b] = make_float2(h0, h1v);
        }
    }
}

// ---------------- K2: bidirectional LSTM layer 1 + fused ReLU/fc1/ReLU/fc2 ----------------
// Wave = 64 samples of one direction (lane = sample for the LSTM). For the fused fc1,
// lanes flip role: lane k owns fc1 output-column k with acc[64] (one per sample).
// Weights arrive as 2 per-lane-distinct coalesced loads/step (L2-resident, 102 KB);
// per-sample v broadcasts go through SGPRs via v_readlane. Zero LDS in the hot loop.
__global__ __launch_bounds__(256) void l1fc_kernel(
    const float2* __restrict__ hin,     // [T][2][B] float2
    const float* __restrict__ wih_f, const float* __restrict__ whh_f,
    const float* __restrict__ bih_f, const float* __restrict__ bhh_f,
    const float* __restrict__ wih_r, const float* __restrict__ whh_r,
    const float* __restrict__ bih_r, const float* __restrict__ bhh_r,
    const float* __restrict__ fc1_wt,   // [400][64]
    const float* __restrict__ fc1_b,
    const float* __restrict__ fc2_w,    // [20][64]
    const float* __restrict__ fc2_b,
    float* __restrict__ out)            // [B][20]
{
    __shared__ float ebuf[128 * 65];    // 33.28 KB: acc exchange + transpose + out repack

    const int tid  = threadIdx.x;
    const int w    = tid >> 6;
    const int lane = tid & 63;
    const int d    = w >> 1;            // direction of this wave
    const int half = w & 1;             // sample half
    const int sm   = half * 64 + lane;  // block-local sample (LSTM role)
    const size_t b = (size_t)blockIdx.x * 128 + sm;

    const float* wih = d ? wih_r : wih_f;
    const float* whh = d ? whh_r : whh_f;
    const float* bih = d ? bih_r : bih_f;
    const float* bhh = d ? bhh_r : bhh_f;

    float wi[32], wh[16], bias[8];
#pragma unroll
    for (int k = 0; k < 32; ++k) wi[k] = wih[k];
#pragma unroll
    for (int k = 0; k < 16; ++k) wh[k] = whh[k];
#pragma unroll
    for (int k = 0; k < 8; ++k) bias[k] = bih[k] + bhh[k];

    const float b1 = fc1_b[lane];       // lane = fc1 column k

    float acc[64];
#pragma unroll
    for (int k = 0; k < 64; ++k) acc[k] = 0.f;

    auto tstep = [&](int st) { return d ? 99 - st : st; };
    auto hload = [&](int t, float2& uF, float2& uR) {
        uF = hin[((size_t)t * 2) * Bn + b];
        uR = hin[((size_t)t * 2 + 1) * Bn + b];
    };
    // fc1 weight row pair for step t, this dir: rows 4t+2d, 4t+2d+1, element lane
    auto wrow = [&](int t) { return fc1_wt + ((size_t)t * 4 + 2 * d) * 64 + lane; };

    // depth-3 h pipeline + 1-step weight prefetch
    float2 aF, aR, p1F, p1R, p2F, p2R;
    hload(tstep(0), aF, aR);
    hload(tstep(1), p1F, p1R);
    hload(tstep(2), p2F, p2R);
    float wt0, wt1;
    { const float* wr = wrow(tstep(0)); wt0 = wr[0]; wt1 = wr[64]; }

    float h0 = 0.f, h1v = 0.f, c0 = 0.f, c1 = 0.f;

#pragma unroll 1
    for (int st = 0; st < 100; ++st) {
        const int sp = (st + 3 <= 99) ? st + 3 : 99;
        float2 nF, nR;
        hload(tstep(sp), nF, nR);
        const float* wr = wrow(tstep((st + 1 <= 99) ? st + 1 : 99));
        const float nw0 = wr[0], nw1 = wr[64];

        float g[8];
#pragma unroll
        for (int k = 0; k < 8; ++k) {
            g[k] = bias[k];
            g[k] = fmaf(wi[k * 4 + 0], aF.x, g[k]);
            g[k] = fmaf(wi[k * 4 + 1], aF.y, g[k]);
            g[k] = fmaf(wi[k * 4 + 2], aR.x, g[k]);
            g[k] = fmaf(wi[k * 4 + 3], aR.y, g[k]);
            g[k] = fmaf(wh[k * 2], h0, fmaf(wh[k * 2 + 1], h1v, g[k]));
        }
        const float i0 = sig_f(g[0]), i1 = sig_f(g[1]);
        const float f0 = sig_f(g[2]), f1 = sig_f(g[3]);
        const float q0 = tanh_f(g[4]), q1 = tanh_f(g[5]);
        const float o0 = sig_f(g[6]), o1 = sig_f(g[7]);
        c0 = fmaf(f0, c0, i0 * q0);
        c1 = fmaf(f1, c1, i1 * q1);
        h0  = o0 * tanh_f(c0);
        h1v = o1 * tanh_f(c1);

        const float v0 = fmaxf(h0, 0.f);
        const float v1 = fmaxf(h1v, 0.f);
        // rank-2 outer-product update: lane k, acc[j] over this wave's 64 samples
#pragma unroll
        for (int j = 0; j < 64; ++j)
            acc[j] = fmaf(wt0, rdlane(v0, j), fmaf(wt1, rdlane(v1, j), acc[j]));

        aF = p1F; aR = p1R; p1F = p2F; p1R = p2R; p2F = nF; p2R = nR;
        wt0 = nw0; wt1 = nw1;
    }

    // ---- merge fwd+rev, bias, relu (ebuf[row][k], stride 65 = conflict-free) ----
    if (d) {
#pragma unroll
        for (int j = 0; j < 64; ++j) ebuf[(half * 64 + j) * 65 + lane] = acc[j];
    }
    __syncthreads();
    if (!d) {
#pragma unroll
        for (int j = 0; j < 64; ++j) {
            const int row = half * 64 + j;
            const float z = acc[j] + ebuf[row * 65 + lane] + b1;
            ebuf[row * 65 + lane] = fmaxf(z, 0.f);
        }
    }
    __syncthreads();

    // ---- fc2: 2 threads/sample, 10 outputs each; z via stride-65 transpose reads ----
    const int sm2 = tid & 127;
    const int og  = (tid >> 7) * 10;    // wave-uniform output group
    float z[64];
#pragma unroll
    for (int k = 0; k < 64; ++k) z[k] = ebuf[sm2 * 65 + k];
    float y[10];
#pragma unroll
    for (int o = 0; o < 10; ++o) {
        float r2 = fc2_b[og + o];
#pragma unroll
        for (int k = 0; k < 64; ++k) r2 = fmaf(fc2_w[(og + o) * 64 + k], z[k], r2);
        y[o] = r2;
    }
    __syncthreads();                    // all z-reads done before repack overwrites
#pragma unroll
    for (int o = 0; o < 10; ++o) ebuf[sm2 * 20 + og + o] = y[o];
    __syncthreads();
    for (int f = tid; f < 2560; f += 256)
        out[(size_t)blockIdx.x * 2560 + f] = ebuf[f];
}

extern "C" void kernel_launch(void* const* d_in, const int* in_sizes, int n_in,
                              void* d_out, int out_size, void* d_ws, size_t ws_size,
                              hipStream_t stream) {
    const float* x = (const float*)d_in[0];
    const float* w_ih_l0  = (const float*)d_in[1];
    const float* w_hh_l0  = (const float*)d_in[2];
    const float* b_ih_l0  = (const float*)d_in[3];
    const float* b_hh_l0  = (const float*)d_in[4];
    const float* w_ih_l0r = (const float*)d_in[5];
    const float* w_hh_l0r = (const float*)d_in[6];
    const float* b_ih_l0r = (const float*)d_in[7];
    const float* b_hh_l0r = (const float*)d_in[8];
    const float* w_ih_l1  = (const float*)d_in[9];
    const float* w_hh_l1  = (const float*)d_in[10];
    const float* b_ih_l1  = (const float*)d_in[11];
    const float* b_hh_l1  = (const float*)d_in[12];
    const float* w_ih_l1r = (const float*)d_in[13];
    const float* w_hh_l1r = (const float*)d_in[14];
    const float* b_ih_l1r = (const float*)d_in[15];
    const float* b_hh_l1r = (const float*)d_in[16];
    const float* fc1_w = (const float*)d_in[17];
    const float* fc1_b = (const float*)d_in[18];
    const float* fc2_w = (const float*)d_in[19];
    const float* fc2_b = (const float*)d_in[20];

    float2* h1f2  = (float2*)d_ws;                                 // [100][2][65536] float2 = 104,857,600 B
    float* fc1_wt = (float*)((char*)d_ws + (size_t)Tn * 4 * Bn * sizeof(float));  // [400][64]

    fc1t_kernel<<<100, 256, 0, stream>>>(fc1_w, fc1_wt);
    l0_kernel<<<512, 256, 0, stream>>>(x,
        w_ih_l0, w_hh_l0, b_ih_l0, b_hh_l0,
        w_ih_l0r, w_hh_l0r, b_ih_l0r, b_hh_l0r, h1f2);
    l1fc_kernel<<<512, 256, 0, stream>>>(h1f2,
        w_ih_l1, w_hh_l1, b_ih_l1, b_hh_l1,
        w_ih_l1r, w_hh_l1r, b_ih_l1r, b_hh_l1r,
        fc1_wt, fc1_b, fc2_w, fc2_b, (float*)d_out);
}

// Round 5
// 468.679 us; speedup vs baseline: 1.0464x; 1.0464x over previous
//
#include <hip/hip_runtime.h>

#define Bn 65536
#define Tn 100
#define Cn 7

typedef short short8 __attribute__((ext_vector_type(8)));   // 8 bf16 = 4 VGPRs (MFMA A/B frag)
typedef float float4v __attribute__((ext_vector_type(4)));  // MFMA C/D frag

__device__ __forceinline__ float fast_rcp(float x) { return __builtin_amdgcn_rcpf(x); }
__device__ __forceinline__ float sig_f(float x) { return fast_rcp(1.f + __expf(-x)); }
// tanh(x) = 1 - 2/(e^{2x}+1): saturates cleanly to +/-1, no inf/inf NaN
__device__ __forceinline__ float tanh_f(float x) { return 1.f - 2.f * fast_rcp(__expf(2.f * x) + 1.f); }
// round-to-nearest-even fp32 -> bf16 (values are finite here; no NaN special-case)
__device__ __forceinline__ unsigned bf16rne(float x) {
    unsigned u = __float_as_uint(x);
    return (u + 0x7fffu + ((u >> 16) & 1u)) >> 16;
}

typedef const __attribute__((address_space(1))) void* gp_t;
typedef __attribute__((address_space(3))) void* sp_t;
__device__ __forceinline__ void async_copy_dw(const float* g, float* l) {
    __builtin_amdgcn_global_load_lds((gp_t)g, (sp_t)l, 4, 0, 0);
}

// ---------------- K0: gather fc1_w into per-(window,dir) bf16 B-panels ----------------
// w2g[w][d][n][kk] (4*2*64*64 bf16): kk=2*tt+i <-> fc1_w[n][4*t+2*d+i],
// t = fwd: 25w+tt, rev: 99-25w-tt; kk in [50,64) zero-padded (K pad to 64 for MFMA).
__global__ void w2prep_kernel(const float* __restrict__ fc1_w, unsigned short* __restrict__ w2g) {
    int idx = blockIdx.x * 256 + threadIdx.x;   // 32768 total
    int w = idx >> 13, d = (idx >> 12) & 1, n = (idx >> 6) & 63, kk = idx & 63;
    int tt = kk >> 1, i = kk & 1;
    int t = d ? (99 - 25 * w - tt) : (25 * w + tt);
    float v = (kk < 50) ? fc1_w[n * 400 + 4 * t + 2 * d + i] : 0.f;
    w2g[idx] = (unsigned short)bf16rne(v);
}

// ---------------- K1: bidirectional LSTM layer 0 (unchanged from round 4) ----------------
__global__ __launch_bounds__(256) void l0_kernel(
    const float* __restrict__ x,
    const float* __restrict__ wih_f, const float* __restrict__ whh_f,
    const float* __restrict__ bih_f, const float* __restrict__ bhh_f,
    const float* __restrict__ wih_r, const float* __restrict__ whh_r,
    const float* __restrict__ bih_r, const float* __restrict__ bhh_r,
    float2* __restrict__ h1f2)
{
    __shared__ float xs[2][2][4480];   // [parity][dir][128 samples * 35 floats]

    const int tid  = threadIdx.x;
    const int rev  = tid >> 7;
    const int s    = tid & 127;
    const int b    = blockIdx.x * 128 + s;
    const int w    = tid >> 6;
    const int lane = tid & 63;
    const int sdir = w >> 1;
    const int half = w & 1;

    const float* wih = rev ? wih_r : wih_f;
    const float* whh = rev ? whh_r : whh_f;
    const float* bih = rev ? bih_r : bih_f;
    const float* bhh = rev ? bhh_r : bhh_f;

    float wi[56], wh[16], bias[8];
#pragma unroll
    for (int k = 0; k < 56; ++k) wi[k] = wih[k];
#pragma unroll
    for (int k = 0; k < 16; ++k) wh[k] = whh[k];
#pragma unroll
    for (int k = 0; k < 8; ++k) bias[k] = bih[k] + bhh[k];

    const int e  = (lane >= 35) ? 1 : 0;
    const int r0 = lane - 35 * e;
    const int s0 = half * 64 + e;
    const float* xsamp = x + (size_t)(blockIdx.x * 128 + s0) * 700;

    auto stage = [&](int ch, int p) {
        const int off = sdir ? (665 - 35 * ch) : (35 * ch);
        const float* g = xsamp + off + r0;
        float* l = &xs[p][sdir][half * 2240 + lane];
        int r = r0;
#pragma unroll
        for (int i = 0; i < 35; ++i) {
            async_copy_dw(g, l);
            l += 64;
            const int c = (r >= 6) ? 1 : 0;
            g += c ? 1394 : 729;
            r += c ? -6 : 29;
        }
    };

    float h0 = 0.f, h1v = 0.f, c0 = 0.f, c1 = 0.f;

    stage(0, 0);
#pragma unroll 1
    for (int ch = 0; ch < 20; ++ch) {
        __builtin_amdgcn_s_waitcnt(0);
        __syncthreads();
        if (ch < 19) stage(ch + 1, (ch + 1) & 1);

        const int t0 = rev ? (95 - 5 * ch) : (5 * ch);
        const float* xbuf = &xs[ch & 1][rev][0];
#pragma unroll 1
        for (int tt = 0; tt < 5; ++tt) {
            const int rr = rev ? (4 - tt) : tt;
            const int t  = t0 + rr;
            const float* xrow = xbuf + s * 35 + rr * 7;

            float g[8];
#pragma unroll
            for (int k = 0; k < 8; ++k) g[k] = bias[k];
#pragma unroll
            for (int c = 0; c < 7; ++c) {
                const float xv = xrow[c];
#pragma unroll
                for (int k = 0; k < 8; ++k) g[k] = fmaf(wi[k * 7 + c], xv, g[k]);
            }
#pragma unroll
            for (int k = 0; k < 8; ++k)
                g[k] = fmaf(wh[k * 2], h0, fmaf(wh[k * 2 + 1], h1v, g[k]));

            const float i0 = sig_f(g[0]), i1 = sig_f(g[1]);
            const float f0 = sig_f(g[2]), f1 = sig_f(g[3]);
            const float q0 = tanh_f(g[4]), q1 = tanh_f(g[5]);
            const float o0 = sig_f(g[6]), o1 = sig_f(g[7]);
            c0 = fmaf(f0, c0, i0 * q0);
            c1 = fmaf(f1, c1, i1 * q1);
            h0  = o0 * tanh_f(c0);
            h1v = o1 * tanh_f(c1);

            h1f2[((size_t)t * 2 + rev) * Bn + b] = make_float2(h0, h1v);
        }
    }
}

// ---------------- K2: LSTM layer 1 + MFMA-fc1 + fc2 ----------------
// 4 windows x 25 steps. LSTM phase: 1 ds_write_b32/step of packed bf16 (v0,v1) into
// A2[d][128][72-stride]; W-panel for the window prefetched (4 float4/thread) under the
// LSTM and ds_written with padded stride. MFMA phase: per wave 2 M-tiles x 4 N-tiles,
// K=64 per dir, acc persistent (32 VGPR). Epilogue: C->LDS, +bias, relu, fc2, out.
__global__ __launch_bounds__(256) void l1fc_kernel(
    const float2* __restrict__ hin,     // [T][2][B] float2
    const float* __restrict__ wih_f, const float* __restrict__ whh_f,
    const float* __restrict__ bih_f, const float* __restrict__ bhh_f,
    const float* __restrict__ wih_r, const float* __restrict__ whh_r,
    const float* __restrict__ bih_r, const float* __restrict__ bhh_r,
    const float4* __restrict__ w2g,     // [4][2][64][64] bf16, as float4[4096]
    const float* __restrict__ fc1_b,
    const float* __restrict__ fc2_w,    // [20][64]
    const float* __restrict__ fc2_b,
    float* __restrict__ out)            // [B][20]
{
    __shared__ unsigned a2[2 * 128 * 36];   // bf16[2][128][72]: stride 36 dw = 144 B (16B-aligned)
    __shared__ unsigned w2[2 * 64 * 36];    // bf16[2][64][72]

    const int tid  = threadIdx.x;
    const int ww   = tid >> 6;
    const int lane = tid & 63;
    const int d    = ww >> 1;            // direction of this wave
    const int half = ww & 1;
    const int sm   = half * 64 + lane;   // block-local sample (LSTM role)
    const size_t b = (size_t)blockIdx.x * 128 + sm;

    const float* wih = d ? wih_r : wih_f;
    const float* whh = d ? whh_r : whh_f;
    const float* bih = d ? bih_r : bih_f;
    const float* bhh = d ? bhh_r : bhh_f;

    float wi[32], wh[16], bias[8];
#pragma unroll
    for (int k = 0; k < 32; ++k) wi[k] = wih[k];
#pragma unroll
    for (int k = 0; k < 16; ++k) wh[k] = whh[k];
#pragma unroll
    for (int k = 0; k < 8; ++k) bias[k] = bih[k] + bhh[k];

    float4v acc[2][4];
#pragma unroll
    for (int mt = 0; mt < 2; ++mt)
#pragma unroll
        for (int nt = 0; nt < 4; ++nt) acc[mt][nt] = (float4v){0.f, 0.f, 0.f, 0.f};

    // zero A2 once (K-pad dwords 25..35 must be 0; they are never overwritten later)
    for (int i2 = tid; i2 < 2 * 128 * 36; i2 += 256) a2[i2] = 0u;
    __syncthreads();

    auto tstep = [&](int st) { return d ? 99 - st : st; };
    auto hload = [&](int t, float2& uF, float2& uR) {
        uF = hin[((size_t)t * 2) * Bn + b];
        uR = hin[((size_t)t * 2 + 1) * Bn + b];
    };

    // depth-3 h1 register pipeline
    float2 aF, aR, p1F, p1R, p2F, p2R;
    hload(tstep(0), aF, aR);
    hload(tstep(1), p1F, p1R);
    hload(tstep(2), p2F, p2R);

    float h0 = 0.f, h1v = 0.f, c0 = 0.f, c1 = 0.f;
    const int cbase = tid * 4;           // this thread's 4 W-panel 16B chunks

#pragma unroll 1
    for (int w = 0; w < 4; ++w) {
        // prefetch this window's W-panel (lands in LDS before the MFMA barrier)
        float4 wl[4];
#pragma unroll
        for (int j = 0; j < 4; ++j) wl[j] = w2g[w * 1024 + cbase + j];

        // ---- LSTM, 25 steps ----
#pragma unroll 1
        for (int tt = 0; tt < 25; ++tt) {
            const int st = 25 * w + tt;
            const int sp = (st + 3 <= 99) ? st + 3 : 99;
            float2 nF, nR;
            hload(tstep(sp), nF, nR);

            float g[8];
#pragma unroll
            for (int k = 0; k < 8; ++k) {
                g[k] = bias[k];
                g[k] = fmaf(wi[k * 4 + 0], aF.x, g[k]);
                g[k] = fmaf(wi[k * 4 + 1], aF.y, g[k]);
                g[k] = fmaf(wi[k * 4 + 2], aR.x, g[k]);
                g[k] = fmaf(wi[k * 4 + 3], aR.y, g[k]);
                g[k] = fmaf(wh[k * 2], h0, fmaf(wh[k * 2 + 1], h1v, g[k]));
            }
            const float i0 = sig_f(g[0]), i1 = sig_f(g[1]);
            const float f0 = sig_f(g[2]), f1 = sig_f(g[3]);
            const float q0 = tanh_f(g[4]), q1 = tanh_f(g[5]);
            const float o0 = sig_f(g[6]), o1 = sig_f(g[7]);
            c0 = fmaf(f0, c0, i0 * q0);
            c1 = fmaf(f1, c1, i1 * q1);
            h0  = o0 * tanh_f(c0);
            h1v = o1 * tanh_f(c1);

            const unsigned vpk = bf16rne(fmaxf(h0, 0.f)) | (bf16rne(fmaxf(h1v, 0.f)) << 16);
            a2[d * 4608 + sm * 36 + tt] = vpk;   // cols 2tt, 2tt+1 of this dir's panel

            aF = p1F; aR = p1R; p1F = p2F; p1R = p2R; p2F = nF; p2R = nR;
        }

        // stage W-panel into LDS with padded stride (36 dw/row)
#pragma unroll
        for (int j = 0; j < 4; ++j) {
            const int c = cbase + j;
            const int dst = (((c >> 9) << 6) + ((c >> 3) & 63)) * 36 + (c & 7) * 4;
            *(float4*)(&w2[dst]) = wl[j];
        }
        __syncthreads();

        // ---- MFMA: C[128x64] += A2[d]·W2[d] for both dirs, K=64 each ----
        {
            const int q = lane >> 4, l16 = lane & 15;
#pragma unroll
            for (int dd = 0; dd < 2; ++dd) {
#pragma unroll
                for (int kt = 0; kt < 2; ++kt) {
                    short8 av[2], bv[4];
#pragma unroll
                    for (int mt = 0; mt < 2; ++mt) {
                        const int srow = ww * 32 + mt * 16 + l16;
                        av[mt] = *(const short8*)&a2[dd * 4608 + srow * 36 + kt * 16 + q * 4];
                    }
#pragma unroll
                    for (int nt = 0; nt < 4; ++nt)
                        bv[nt] = *(const short8*)&w2[(dd * 64 + nt * 16 + l16) * 36 + kt * 16 + q * 4];
#pragma unroll
                    for (int mt = 0; mt < 2; ++mt)
#pragma unroll
                        for (int nt = 0; nt < 4; ++nt)
                            acc[mt][nt] = __builtin_amdgcn_mfma_f32_16x16x32_bf16(
                                av[mt], bv[nt], acc[mt][nt], 0, 0, 0);
                }
            }
        }
        __syncthreads();   // A2/W2 free for next window
    }

    // ---- epilogue: C -> LDS (reuse a2), +bias, relu, fc2, out ----
    {
        const int q = lane >> 4, l16 = lane & 15;
        float* eb = (float*)a2;            // [128][65]
#pragma unroll
        for (int mt = 0; mt < 2; ++mt)
#pragma unroll
            for (int nt = 0; nt < 4; ++nt)
#pragma unroll
                for (int r = 0; r < 4; ++r) {
                    const int sl = ww * 32 + mt * 16 + q * 4 + r;  // C row = sample
                    const int cl = nt * 16 + l16;                  // C col = fc1 out
                    eb[sl * 65 + cl] = acc[mt][nt][r];
                }
    }
    __syncthreads();

    const float* eb = (const float*)a2;
    const int sm2 = tid & 127;
    const int og  = (tid >> 7) * 10;       // wave-uniform output group
    float z[64];
#pragma unroll
    for (int k = 0; k < 64; ++k) z[k] = fmaxf(eb[sm2 * 65 + k] + fc1_b[k], 0.f);
    float y[10];
#pragma unroll
    for (int o = 0; o < 10; ++o) {
        float r2 = fc2_b[og + o];
#pragma unroll
        for (int k = 0; k < 64; ++k) r2 = fmaf(fc2_w[(og + o) * 64 + k], z[k], r2);
        y[o] = r2;
    }
    __syncthreads();                        // all z-reads done before repack
    float* ebw = (float*)a2;
#pragma unroll
    for (int o = 0; o < 10; ++o) ebw[sm2 * 20 + og + o] = y[o];
    __syncthreads();
    for (int f = tid; f < 2560; f += 256)
        out[(size_t)blockIdx.x * 2560 + f] = ebw[f];
}

extern "C" void kernel_launch(void* const* d_in, const int* in_sizes, int n_in,
                              void* d_out, int out_size, void* d_ws, size_t ws_size,
                              hipStream_t stream) {
    const float* x = (const float*)d_in[0];
    const float* w_ih_l0  = (const float*)d_in[1];
    const float* w_hh_l0  = (const float*)d_in[2];
    const float* b_ih_l0  = (const float*)d_in[3];
    const float* b_hh_l0  = (const float*)d_in[4];
    const float* w_ih_l0r = (const float*)d_in[5];
    const float* w_hh_l0r = (const float*)d_in[6];
    const float* b_ih_l0r = (const float*)d_in[7];
    const float* b_hh_l0r = (const float*)d_in[8];
    const float* w_ih_l1  = (const float*)d_in[9];
    const float* w_hh_l1  = (const float*)d_in[10];
    const float* b_ih_l1  = (const float*)d_in[11];
    const float* b_hh_l1  = (const float*)d_in[12];
    const float* w_ih_l1r = (const float*)d_in[13];
    const float* w_hh_l1r = (const float*)d_in[14];
    const float* b_ih_l1r = (const float*)d_in[15];
    const float* b_hh_l1r = (const float*)d_in[16];
    const float* fc1_w = (const float*)d_in[17];
    const float* fc1_b = (const float*)d_in[18];
    const float* fc2_w = (const float*)d_in[19];
    const float* fc2_b = (const float*)d_in[20];

    float2* h1f2 = (float2*)d_ws;   // [100][2][65536] float2 = 104,857,600 B
    unsigned short* w2g = (unsigned short*)((char*)d_ws + (size_t)Tn * 4 * Bn * sizeof(float)); // 65,536 B

    w2prep_kernel<<<128, 256, 0, stream>>>(fc1_w, w2g);
    l0_kernel<<<512, 256, 0, stream>>>(x,
        w_ih_l0, w_hh_l0, b_ih_l0, b_hh_l0,
        w_ih_l0r, w_hh_l0r, b_ih_l0r, b_hh_l0r, h1f2);
    l1fc_kernel<<<512, 256, 0, stream>>>(h1f2,
        w_ih_l1, w_hh_l1, b_ih_l1, b_hh_l1,
        w_ih_l1r, w_hh_l1r, b_ih_l1r, b_hh_l1r,
        (const float4*)w2g, fc1_b, fc2_w, fc2_b, (float*)d_out);
}

// Round 6
// 438.279 us; speedup vs baseline: 1.1190x; 1.0694x over previous
//
#include <hip/hip_runtime.h>

#define Bn 65536
#define Tn 100
#define Cn 7

typedef short short8 __attribute__((ext_vector_type(8)));   // 8 bf16 = 4 VGPRs (MFMA A/B frag)
typedef float float4v __attribute__((ext_vector_type(4)));  // MFMA C/D frag

__device__ __forceinline__ float fast_rcp(float x) { return __builtin_amdgcn_rcpf(x); }
__device__ __forceinline__ float sig_f(float x) { return fast_rcp(1.f + __expf(-x)); }
__device__ __forceinline__ float tanh_f(float x) { return 1.f - 2.f * fast_rcp(__expf(2.f * x) + 1.f); }
// round-to-nearest-even fp32 -> bf16 (finite values only)
__device__ __forceinline__ unsigned bf16rne(float x) {
    unsigned u = __float_as_uint(x);
    return (u + 0x7fffu + ((u >> 16) & 1u)) >> 16;
}
__device__ __forceinline__ float bf_lo(unsigned u) { return __uint_as_float(u << 16); }
__device__ __forceinline__ float bf_hi(unsigned u) { return __uint_as_float(u & 0xffff0000u); }

typedef const __attribute__((address_space(1))) void* gp_t;
typedef __attribute__((address_space(3))) void* sp_t;
__device__ __forceinline__ void async_copy_dw(const void* g, void* l) {
    __builtin_amdgcn_global_load_lds((gp_t)g, (sp_t)l, 4, 0, 0);
}

// ---------------- K0: gather fc1_w into per-(window,dir) bf16 B-panels ----------------
// w2g[10][2][64][32] bf16: kk=2*tt+i <-> fc1_w[n][4*t+2*d+i], t = d? 99-10w-tt : 10w+tt;
// kk in [20,32) zero (K pad to 32 for one 16x16x32 MFMA per tile).
__global__ void w2prep_kernel(const float* __restrict__ fc1_w, unsigned short* __restrict__ w2g) {
    int idx = blockIdx.x * 256 + threadIdx.x;   // 40960 total
    int w  = idx >> 12;
    int d  = (idx >> 11) & 1;
    int n  = (idx >> 5) & 63;
    int kk = idx & 31;
    int tt = kk >> 1, i = kk & 1;
    int t  = d ? (99 - 10 * w - tt) : (10 * w + tt);
    float v = (kk < 20) ? fc1_w[n * 400 + 4 * t + 2 * d + i] : 0.f;
    w2g[idx] = (unsigned short)bf16rne(v);
}

// ---------------- K1: bidirectional LSTM layer 0 ----------------
// As round 5, plus: h1 packed bf16 [T][2][B] uint (1 store/step, half the bytes), and the
// chunk barrier waits vmcnt(5) — drains the 35 staged loads but leaves the 5 fresh h1
// stores in flight (no store-ack stall). sched_barrier pins load/store issue order.
__global__ __launch_bounds__(256) void l0_kernel(
    const float* __restrict__ x,
    const float* __restrict__ wih_f, const float* __restrict__ whh_f,
    const float* __restrict__ bih_f, const float* __restrict__ bhh_f,
    const float* __restrict__ wih_r, const float* __restrict__ whh_r,
    const float* __restrict__ bih_r, const float* __restrict__ bhh_r,
    unsigned* __restrict__ h1u)
{
    __shared__ float xs[2][2][4480];   // [parity][dir][128 samples * 35 floats]

    const int tid  = threadIdx.x;
    const int rev  = tid >> 7;
    const int s    = tid & 127;
    const int b    = blockIdx.x * 128 + s;
    const int w    = tid >> 6;
    const int lane = tid & 63;
    const int sdir = w >> 1;
    const int half = w & 1;

    const float* wih = rev ? wih_r : wih_f;
    const float* whh = rev ? whh_r : whh_f;
    const float* bih = rev ? bih_r : bih_f;
    const float* bhh = rev ? bhh_r : bhh_f;

    float wi[56], wh[16], bias[8];
#pragma unroll
    for (int k = 0; k < 56; ++k) wi[k] = wih[k];
#pragma unroll
    for (int k = 0; k < 16; ++k) wh[k] = whh[k];
#pragma unroll
    for (int k = 0; k < 8; ++k) bias[k] = bih[k] + bhh[k];

    const int e  = (lane >= 35) ? 1 : 0;
    const int r0 = lane - 35 * e;
    const int s0 = half * 64 + e;
    const float* xsamp = x + (size_t)(blockIdx.x * 128 + s0) * 700;

    auto stage = [&](int ch, int p) {
        const int off = sdir ? (665 - 35 * ch) : (35 * ch);
        const float* g = xsamp + off + r0;
        float* l = &xs[p][sdir][half * 2240 + lane];
        int r = r0;
#pragma unroll
        for (int i = 0; i < 35; ++i) {
            async_copy_dw(g, l);
            l += 64;
            const int c = (r >= 6) ? 1 : 0;
            g += c ? 1394 : 729;
            r += c ? -6 : 29;
        }
    };

    float h0 = 0.f, h1v = 0.f, c0 = 0.f, c1 = 0.f;

    stage(0, 0);
#pragma unroll 1
    for (int ch = 0; ch < 20; ++ch) {
        // vmcnt(5): drain the 35 chunk loads, leave the 5 newest (h1 stores) in flight
        if (ch == 0) __builtin_amdgcn_s_waitcnt(0x0F70);
        else         __builtin_amdgcn_s_waitcnt(0x0F75);
        __syncthreads();
        if (ch < 19) stage(ch + 1, (ch + 1) & 1);
        __builtin_amdgcn_sched_barrier(0);   // keep stage loads older than compute's stores

        const int t0 = rev ? (95 - 5 * ch) : (5 * ch);
        const float* xbuf = &xs[ch & 1][rev][0];
#pragma unroll 1
        for (int tt = 0; tt < 5; ++tt) {
            const int rr = rev ? (4 - tt) : tt;
            const int t  = t0 + rr;
            const float* xrow = xbuf + s * 35 + rr * 7;

            float g[8];
#pragma unroll
            for (int k = 0; k < 8; ++k) g[k] = bias[k];
#pragma unroll
            for (int c = 0; c < 7; ++c) {
                const float xv = xrow[c];
#pragma unroll
                for (int k = 0; k < 8; ++k) g[k] = fmaf(wi[k * 7 + c], xv, g[k]);
            }
#pragma unroll
            for (int k = 0; k < 8; ++k)
                g[k] = fmaf(wh[k * 2], h0, fmaf(wh[k * 2 + 1], h1v, g[k]));

            const float i0 = sig_f(g[0]), i1 = sig_f(g[1]);
            const float f0 = sig_f(g[2]), f1 = sig_f(g[3]);
            const float q0 = tanh_f(g[4]), q1 = tanh_f(g[5]);
            const float o0 = sig_f(g[6]), o1 = sig_f(g[7]);
            c0 = fmaf(f0, c0, i0 * q0);
            c1 = fmaf(f1, c1, i1 * q1);
            h0  = o0 * tanh_f(c0);
            h1v = o1 * tanh_f(c1);

            h1u[((size_t)t * 2 + rev) * Bn + b] = bf16rne(h0) | (bf16rne(h1v) << 16);
        }
    }
}

// ---------------- K2: LSTM layer 1 + MFMA-fc1 + fc2 ----------------
// 10 windows x 10 steps. h1 slab (2 planes x 2 dirs x 10 t x 128 samples, packed bf16)
// double-buffered via async global_load_lds -> the step loop has ZERO global loads.
// a2 panel stride 20 dw (16B-aligned b128, <=2-way banks). MFMA K=32 per window per dir.
__global__ __launch_bounds__(256) void l1fc_kernel(
    const unsigned* __restrict__ hin,   // [T][2][B] packed bf16 pairs
    const float* __restrict__ wih_f, const float* __restrict__ whh_f,
    const float* __restrict__ bih_f, const float* __restrict__ bhh_f,
    const float* __restrict__ wih_r, const float* __restrict__ whh_r,
    const float* __restrict__ bih_r, const float* __restrict__ bhh_r,
    const unsigned* __restrict__ w2g,   // [10][2][64][32] bf16 = [10][2][64][16] dw
    const float* __restrict__ fc1_b,
    const float* __restrict__ fc2_w,    // [20][64]
    const float* __restrict__ fc2_b,
    float* __restrict__ out)            // [B][20]
{
    __shared__ unsigned smem[19456];    // 77,824 B -> 2 blocks/CU
    unsigned* a2  = smem;               // [2][128][20] dw (bf16 pairs; cols 10..15 zero K-pad)
    unsigned* w2b = smem + 5120;        // [2 buf][2 d][64][16] dw
    unsigned* hst = smem + 9216;        // [2 buf][2 d][2 p][10][128] dw

    const int tid  = threadIdx.x;
    const int ww   = tid >> 6;
    const int lane = tid & 63;
    const int d    = ww >> 1;
    const int half = ww & 1;
    const int sm   = half * 64 + lane;
    const int b0   = blockIdx.x * 128;

    const float* wih = d ? wih_r : wih_f;
    const float* whh = d ? whh_r : whh_f;
    const float* bih = d ? bih_r : bih_f;
    const float* bhh = d ? bhh_r : bhh_f;

    float wi[32], wh[16], bias[8];
#pragma unroll
    for (int k = 0; k < 32; ++k) wi[k] = wih[k];
#pragma unroll
    for (int k = 0; k < 16; ++k) wh[k] = whh[k];
#pragma unroll
    for (int k = 0; k < 8; ++k) bias[k] = bih[k] + bhh[k];

    float4v acc[2][4];
#pragma unroll
    for (int mt = 0; mt < 2; ++mt)
#pragma unroll
        for (int nt = 0; nt < 4; ++nt) acc[mt][nt] = (float4v){0.f, 0.f, 0.f, 0.f};

    for (int i = tid; i < 5120; i += 256) a2[i] = 0u;   // zero incl. K-pad cols

    // stage h slab for window w into buffer pb: rows R=[dd][p][j] of 128 dwords
    auto stage_h = [&](int w, int pb) {
        unsigned* dst = hst + pb * 5120;
        const int Rb = tid >> 7;           // 0/1
        const int s  = tid & 127;
#pragma unroll
        for (int i = 0; i < 20; ++i) {
            const int R  = Rb + 2 * i;     // 0..39
            const int dd = (R >= 20) ? 1 : 0;
            const int r2 = R - 20 * dd;
            const int p  = (r2 >= 10) ? 1 : 0;
            const int j  = r2 - 10 * p;
            const int t  = dd ? (99 - (10 * w + j)) : (10 * w + j);
            async_copy_dw(hin + ((size_t)t * 2 + p) * Bn + b0 + s, dst + R * 128 + s);
        }
    };
    auto stage_w = [&](int w, int pb) {
        const unsigned* src = w2g + w * 2048;
        unsigned* dst = w2b + pb * 2048;
#pragma unroll
        for (int i = 0; i < 8; ++i)
            async_copy_dw(src + i * 256 + tid, dst + i * 256 + tid);
    };

    stage_h(0, 0); stage_w(0, 0);

    float h0 = 0.f, h1v = 0.f, c0 = 0.f, c1 = 0.f;
    const int q = lane >> 4, l16 = lane & 15;

#pragma unroll 1
    for (int w = 0; w < 10; ++w) {
        __builtin_amdgcn_s_waitcnt(0x0F70);   // this window's slabs arrived
        __syncthreads();                      // (also covers a2-zero at w=0)
        if (w < 9) { stage_h(w + 1, (w + 1) & 1); stage_w(w + 1, (w + 1) & 1); }

        // ---- 10 LSTM steps (LDS-only inputs) ----
        const unsigned* hb = hst + (w & 1) * 5120 + d * 2560;
#pragma unroll 1
        for (int j = 0; j < 10; ++j) {
            const unsigned uF = hb[j * 128 + sm];
            const unsigned uR = hb[1280 + j * 128 + sm];
            const float aF0 = bf_lo(uF), aF1 = bf_hi(uF);
            const float aR0 = bf_lo(uR), aR1 = bf_hi(uR);

            float g[8];
#pragma unroll
            for (int k = 0; k < 8; ++k) {
                g[k] = bias[k];
                g[k] = fmaf(wi[k * 4 + 0], aF0, g[k]);
                g[k] = fmaf(wi[k * 4 + 1], aF1, g[k]);
                g[k] = fmaf(wi[k * 4 + 2], aR0, g[k]);
                g[k] = fmaf(wi[k * 4 + 3], aR1, g[k]);
                g[k] = fmaf(wh[k * 2], h0, fmaf(wh[k * 2 + 1], h1v, g[k]));
            }
            const float i0 = sig_f(g[0]), i1 = sig_f(g[1]);
            const float f0 = sig_f(g[2]), f1 = sig_f(g[3]);
            const float q0 = tanh_f(g[4]), q1 = tanh_f(g[5]);
            const float o0 = sig_f(g[6]), o1 = sig_f(g[7]);
            c0 = fmaf(f0, c0, i0 * q0);
            c1 = fmaf(f1, c1, i1 * q1);
            h0  = o0 * tanh_f(c0);
            h1v = o1 * tanh_f(c1);

            a2[d * 2560 + sm * 20 + j] = bf16rne(fmaxf(h0, 0.f)) | (bf16rne(fmaxf(h1v, 0.f)) << 16);
        }
        __syncthreads();   // a2 complete

        // ---- MFMA: C[128x64] += A2[dd]·W2[dd]^T, K=32, both dirs ----
        {
            const unsigned* wb = w2b + (w & 1) * 2048;
#pragma unroll
            for (int dd = 0; dd < 2; ++dd) {
                short8 av[2], bv[4];
#pragma unroll
                for (int mt = 0; mt < 2; ++mt)
                    av[mt] = *(const short8*)&a2[dd * 2560 + (ww * 32 + mt * 16 + l16) * 20 + q * 4];
#pragma unroll
                for (int nt = 0; nt < 4; ++nt)
                    bv[nt] = *(const short8*)&wb[dd * 1024 + (nt * 16 + l16) * 16 + q * 4];
#pragma unroll
                for (int mt = 0; mt < 2; ++mt)
#pragma unroll
                    for (int nt = 0; nt < 4; ++nt)
                        acc[mt][nt] = __builtin_amdgcn_mfma_f32_16x16x32_bf16(
                            av[mt], bv[nt], acc[mt][nt], 0, 0, 0);
            }
        }
        // next window's top barrier separates these MFMA reads from the next a2 writes
    }
    __syncthreads();

    // ---- epilogue: C -> LDS, +bias, relu, fc2, out ----
    {
        float* eb = (float*)smem;          // [128][65]
#pragma unroll
        for (int mt = 0; mt < 2; ++mt)
#pragma unroll
            for (int nt = 0; nt < 4; ++nt)
#pragma unroll
                for (int r = 0; r < 4; ++r) {
                    const int sl = ww * 32 + mt * 16 + q * 4 + r;
                    const int cl = nt * 16 + l16;
                    eb[sl * 65 + cl] = acc[mt][nt][r];
                }
    }
    __syncthreads();

    const float* eb = (const float*)smem;
    const int sm2 = tid & 127;
    const int og  = (tid >> 7) * 10;
    float z[64];
#pragma unroll
    for (int k = 0; k < 64; ++k) z[k] = fmaxf(eb[sm2 * 65 + k] + fc1_b[k], 0.f);
    float y[10];
#pragma unroll
    for (int o = 0; o < 10; ++o) {
        float r2 = fc2_b[og + o];
#pragma unroll
        for (int k = 0; k < 64; ++k) r2 = fmaf(fc2_w[(og + o) * 64 + k], z[k], r2);
        y[o] = r2;
    }
    __syncthreads();
    float* ebw = (float*)smem;
#pragma unroll
    for (int o = 0; o < 10; ++o) ebw[sm2 * 20 + og + o] = y[o];
    __syncthreads();
    for (int f = tid; f < 2560; f += 256)
        out[(size_t)blockIdx.x * 2560 + f] = ebw[f];
}

extern "C" void kernel_launch(void* const* d_in, const int* in_sizes, int n_in,
                              void* d_out, int out_size, void* d_ws, size_t ws_size,
                              hipStream_t stream) {
    const float* x = (const float*)d_in[0];
    const float* w_ih_l0  = (const float*)d_in[1];
    const float* w_hh_l0  = (const float*)d_in[2];
    const float* b_ih_l0  = (const float*)d_in[3];
    const float* b_hh_l0  = (const float*)d_in[4];
    const float* w_ih_l0r = (const float*)d_in[5];
    const float* w_hh_l0r = (const float*)d_in[6];
    const float* b_ih_l0r = (const float*)d_in[7];
    const float* b_hh_l0r = (const float*)d_in[8];
    const float* w_ih_l1  = (const float*)d_in[9];
    const float* w_hh_l1  = (const float*)d_in[10];
    const float* b_ih_l1  = (const float*)d_in[11];
    const float* b_hh_l1  = (const float*)d_in[12];
    const float* w_ih_l1r = (const float*)d_in[13];
    const float* w_hh_l1r = (const float*)d_in[14];
    const float* b_ih_l1r = (const float*)d_in[15];
    const float* b_hh_l1r = (const float*)d_in[16];
    const float* fc1_w = (const float*)d_in[17];
    const float* fc1_b = (const float*)d_in[18];
    const float* fc2_w = (const float*)d_in[19];
    const float* fc2_b = (const float*)d_in[20];

    unsigned* h1u = (unsigned*)d_ws;                                // [100][2][65536] u32 = 52,428,800 B
    unsigned short* w2g = (unsigned short*)((char*)d_ws + (size_t)Tn * 2 * Bn * 4);  // 81,920 B

    w2prep_kernel<<<160, 256, 0, stream>>>(fc1_w, w2g);
    l0_kernel<<<512, 256, 0, stream>>>(x,
        w_ih_l0, w_hh_l0, b_ih_l0, b_hh_l0,
        w_ih_l0r, w_hh_l0r, b_ih_l0r, b_hh_l0r, h1u);
    l1fc_kernel<<<512, 256, 0, stream>>>(h1u,
        w_ih_l1, w_hh_l1, b_ih_l1, b_hh_l1,
        w_ih_l1r, w_hh_l1r, b_ih_l1r, b_hh_l1r,
        (const unsigned*)w2g, fc1_b, fc2_w, fc2_b, (float*)d_out);
}